// Round 1
// baseline (1574.790 us; speedup 1.0000x reference)
//
#include <hip/hip_runtime.h>
#include <stdint.h>

// ---------------- problem constants ----------------
#define NBLK   64          // workgroups (persistent, all co-resident: 64 << 256 CUs)
#define NTHR   512         // 8 waves
#define ROWS   16          // batch rows per WG  (64*16 = 1024)
#define S      512         // state dim == hidden dim
#define STRD   520         // LDS act row stride in bf16 elems (pad 8 -> conflict-free)
#define KSZ    (1024*512)  // floats per k-slot
#define NELEMF 524288.0f

typedef __attribute__((ext_vector_type(4))) float  f32x4;
typedef __attribute__((ext_vector_type(8))) short  short8;
typedef __attribute__((ext_vector_type(8))) __bf16 bf16x8;
union frag_u { short8 s; bf16x8 b; };

// ---------------- d_ws layout (bytes) ----------------
#define CTR_OFF 0
#define RED_OFF 256                           // floats: d0p[64] d1p[64] d2p[64] errp[20][64]
#define WB_OFF  16384                         // bf16 [3][512][512], layout [n][k]
#define Y5_OFF  (WB_OFF + 3*512*512*2)        // f32 [1024][512] alternate-y buffer
#define K_OFF   (Y5_OFF + KSZ*4)              // f32 [7][1024][512] k-slots
// total ~17.6 MB

// dopri5 tableau (f32)
static __device__ const float C_A2[1] = {0.2f};
static __device__ const float C_A3[2] = {3.f/40.f, 9.f/40.f};
static __device__ const float C_A4[3] = {44.f/45.f, -56.f/15.f, 32.f/9.f};
static __device__ const float C_A5[4] = {19372.f/6561.f, -25360.f/2187.f, 64448.f/6561.f, -212.f/729.f};
static __device__ const float C_A6[5] = {9017.f/3168.f, -355.f/33.f, 46732.f/5247.f, 49.f/176.f, -5103.f/18656.f};
static __device__ const float C_B5[6] = {35.f/384.f, 0.f, 500.f/1113.f, 125.f/192.f, -2187.f/6784.f, 11.f/84.f};
#define E1f (71.f/57600.f)
#define E3f (-71.f/16695.f)
#define E4f (71.f/1920.f)
#define E5f (-17253.f/339200.f)
#define E6f (22.f/525.f)
#define E7f (-1.f/40.f)

__device__ __forceinline__ short f2bf(float f) {
  union { float f; uint32_t u; } v; v.f = f;
  uint32_t u = v.u;
  return (short)((u + 0x7fffu + ((u >> 16) & 1u)) >> 16);   // RNE
}

// grid barrier: monotonic counter, uniform call count across blocks
__device__ __forceinline__ void gbar(unsigned* ctr, unsigned& target) {
  __threadfence();
  __syncthreads();
  if (threadIdx.x == 0) {
    __hip_atomic_fetch_add(ctr, 1u, __ATOMIC_ACQ_REL, __HIP_MEMORY_SCOPE_AGENT);
    while (__hip_atomic_load(ctr, __ATOMIC_ACQUIRE, __HIP_MEMORY_SCOPE_AGENT) < target) {
      __builtin_amdgcn_s_sleep(2);
    }
  }
  __syncthreads();
  __threadfence();
  target += NBLK;
}

__device__ __forceinline__ float block_sum(float v, float* sred) {
  #pragma unroll
  for (int o = 32; o > 0; o >>= 1) v += __shfl_down(v, o, 64);
  const int wv = threadIdx.x >> 6;
  if ((threadIdx.x & 63) == 0) sred[wv] = v;
  __syncthreads();
  if (threadIdx.x == 0) {
    float s = 0.f;
    for (int i = 0; i < 8; ++i) s += sred[i];
    sred[8] = s;
  }
  __syncthreads();
  float r = sred[8];
  __syncthreads();
  return r;
}

// One 16x512 @ 512x512 layer: in LDS (bf16) -> out LDS (bf16) or global f32.
// Wb layout [n][k] bf16. MFMA 16x16x32: A row=lane&15, k=(lane>>4)*8+j;
// B col=lane&15, same k; D col=lane&15, row=(lane>>4)*4+reg.
__device__ __forceinline__ void layer_g(const short (*inT)[STRD],
                                        const short* __restrict__ Wb,
                                        const float* __restrict__ bias,
                                        short (*outT)[STRD], float* __restrict__ gOut,
                                        const bool relu) {
  const int lane = threadIdx.x & 63;
  const int wv   = threadIdx.x >> 6;
  const int m16  = lane & 15;
  const int kg   = lane >> 4;
  const int n0   = wv * 64;
  f32x4 acc[4];
  #pragma unroll
  for (int i = 0; i < 4; ++i) acc[i] = f32x4{0.f, 0.f, 0.f, 0.f};
  const short* wrow0 = Wb + (size_t)(n0 + m16) * S;
  #pragma unroll
  for (int kt = 0; kt < 16; ++kt) {
    const int kb = kt * 32 + kg * 8;
    frag_u a; a.s = *(const short8*)&inT[m16][kb];
    #pragma unroll
    for (int nt = 0; nt < 4; ++nt) {
      frag_u bq; bq.s = *(const short8*)(wrow0 + (size_t)nt * 16 * S + kb);
      acc[nt] = __builtin_amdgcn_mfma_f32_16x16x32_bf16(a.b, bq.b, acc[nt], 0, 0, 0);
    }
  }
  #pragma unroll
  for (int nt = 0; nt < 4; ++nt) {
    const int col = n0 + nt * 16 + m16;
    const float bv = bias[col];
    #pragma unroll
    for (int r = 0; r < 4; ++r) {
      float v = acc[nt][r] + bv;
      if (relu) v = fmaxf(v, 0.f);
      const int orow = kg * 4 + r;
      if (outT) outT[orow][col] = f2bf(v);
      else      gOut[(size_t)orow * S + col] = v;
    }
  }
}

__device__ __forceinline__ void feval3(short (*A)[STRD], short (*B)[STRD],
                                       const short* Wb,
                                       const float* b1, const float* b2, const float* b3,
                                       float* kout) {
  layer_g(A, Wb,           b1, B, nullptr, true);
  __syncthreads();
  layer_g(B, Wb + S * S,   b2, A, nullptr, true);
  __syncthreads();
  layer_g(A, Wb + 2 * S * S, b3, nullptr, kout, false);
  __syncthreads();
}

// build yi = y + dtc * sum(coef[j] * k[slot(j)]) into LDS bf16 act; optional f32 copy out
__device__ __forceinline__ void build_act(short (*A)[STRD],
                                          const float* __restrict__ yloc,
                                          const float* __restrict__ kloc,
                                          const float* coef, int nk, int s1, int s7,
                                          float dtc, float* __restrict__ y5loc) {
  const int t = threadIdx.x;
  const int row = t >> 5;
  const int c0 = (t & 31) << 4;
  const size_t off = (size_t)row * S + c0;
  f32x4 v[4];
  {
    const f32x4* yv = (const f32x4*)(yloc + off);
    #pragma unroll
    for (int i = 0; i < 4; ++i) v[i] = yv[i];
  }
  for (int j = 0; j < nk; ++j) {
    const float c = coef[j];
    if (c == 0.f) continue;
    const int slot = (j == 0) ? s1 : ((j == 6) ? s7 : j);
    const float cd = c * dtc;
    const f32x4* kv = (const f32x4*)(kloc + (size_t)slot * KSZ + off);
    #pragma unroll
    for (int i = 0; i < 4; ++i) v[i] += cd * kv[i];
  }
  if (y5loc) {
    f32x4* ov = (f32x4*)(y5loc + off);
    #pragma unroll
    for (int i = 0; i < 4; ++i) ov[i] = v[i];
  }
  short8 p0, p1;
  #pragma unroll
  for (int e = 0; e < 4; ++e) {
    p0[e]     = f2bf(v[0][e]);
    p0[4 + e] = f2bf(v[1][e]);
    p1[e]     = f2bf(v[2][e]);
    p1[4 + e] = f2bf(v[3][e]);
  }
  *(short8*)&A[row][c0]     = p0;
  *(short8*)&A[row][c0 + 8] = p1;
  __syncthreads();
}

__device__ __forceinline__ void sumsq_init(const float* yloc, const float* f0loc,
                                           float& s_y, float& s_f) {
  const int t = threadIdx.x;
  const size_t off = (size_t)(t >> 5) * S + ((t & 31) << 4);
  const f32x4* yv = (const f32x4*)(yloc + off);
  const f32x4* fv = (const f32x4*)(f0loc + off);
  float ay = 0.f, af = 0.f;
  #pragma unroll
  for (int i = 0; i < 4; ++i) {
    #pragma unroll
    for (int q = 0; q < 4; ++q) {
      float y = yv[i][q], f = fv[i][q];
      float sc = 1e-3f + 1e-3f * fabsf(y);
      float a = y / sc, b = f / sc;
      ay += a * a; af += b * b;
    }
  }
  s_y = ay; s_f = af;
}

__device__ __forceinline__ float sumsq_d2(const float* yloc, const float* f0loc,
                                          const float* f1loc) {
  const int t = threadIdx.x;
  const size_t off = (size_t)(t >> 5) * S + ((t & 31) << 4);
  const f32x4* yv = (const f32x4*)(yloc + off);
  const f32x4* f0 = (const f32x4*)(f0loc + off);
  const f32x4* f1 = (const f32x4*)(f1loc + off);
  float acc = 0.f;
  #pragma unroll
  for (int i = 0; i < 4; ++i) {
    #pragma unroll
    for (int q = 0; q < 4; ++q) {
      float sc = 1e-3f + 1e-3f * fabsf(yv[i][q]);
      float d = (f1[i][q] - f0[i][q]) / sc;
      acc += d * d;
    }
  }
  return acc;
}

__device__ __forceinline__ float sumsq_err(const float* yloc, const float* y5loc,
                                           const float* kloc, int s1, int s7, float dtc) {
  const int t = threadIdx.x;
  const size_t off = (size_t)(t >> 5) * S + ((t & 31) << 4);
  const f32x4* yv  = (const f32x4*)(yloc + off);
  const f32x4* y5v = (const f32x4*)(y5loc + off);
  const f32x4* k1 = (const f32x4*)(kloc + (size_t)s1 * KSZ + off);
  const f32x4* k3 = (const f32x4*)(kloc + (size_t)2  * KSZ + off);
  const f32x4* k4 = (const f32x4*)(kloc + (size_t)3  * KSZ + off);
  const f32x4* k5 = (const f32x4*)(kloc + (size_t)4  * KSZ + off);
  const f32x4* k6 = (const f32x4*)(kloc + (size_t)5  * KSZ + off);
  const f32x4* k7 = (const f32x4*)(kloc + (size_t)s7 * KSZ + off);
  float acc = 0.f;
  #pragma unroll
  for (int i = 0; i < 4; ++i) {
    f32x4 e = E1f * k1[i] + E3f * k3[i] + E4f * k4[i] + E5f * k5[i] + E6f * k6[i] + E7f * k7[i];
    #pragma unroll
    for (int q = 0; q < 4; ++q) {
      float ee = dtc * e[q];
      float sc = 1e-3f + 1e-3f * fmaxf(fabsf(yv[i][q]), fabsf(y5v[i][q]));
      float r = ee / sc;
      acc += r * r;
    }
  }
  return acc;
}

extern "C" __global__ void node_zero(unsigned* ctr) {
  if (threadIdx.x == 0) *ctr = 0u;
}

extern "C" __global__ void __launch_bounds__(NTHR)
node_main(const float* __restrict__ x,
          const float* __restrict__ W1, const float* __restrict__ b1,
          const float* __restrict__ W2, const float* __restrict__ b2,
          const float* __restrict__ W3, const float* __restrict__ b3,
          float* __restrict__ out, unsigned char* __restrict__ wsb) {
  __shared__ short A[ROWS][STRD];
  __shared__ short B[ROWS][STRD];
  __shared__ float strans[64][68];
  __shared__ float sred[16];
  __shared__ float sbc[4];

  unsigned* ctr = (unsigned*)(wsb + CTR_OFF);
  float*    red = (float*)(wsb + RED_OFF);
  short*    Wb  = (short*)(wsb + WB_OFF);
  float*    yB  = (float*)(wsb + Y5_OFF);
  float*    kb  = (float*)(wsb + K_OFF);

  const int wg = blockIdx.x;
  const int r0 = wg * ROWS;
  unsigned target = NBLK;

  float* yloc = out + (size_t)r0 * S;   // current y (starts in d_out)
  float* yAlt = yB  + (size_t)r0 * S;   // alternate buffer
  float* kloc = kb  + (size_t)r0 * S;   // k slots, + slot*KSZ

  // ---- Phase A: y0 = [x, 0]; transpose+convert weights to bf16 [n][k] ----
  {
    const int t = threadIdx.x;
    const int row = t >> 5, c0 = (t & 31) << 4;
    f32x4* dst = (f32x4*)(yloc + (size_t)row * S + c0);
    if (c0 < 448) {
      const f32x4* src = (const f32x4*)(x + (size_t)(r0 + row) * 448 + c0);
      #pragma unroll
      for (int i = 0; i < 4; ++i) dst[i] = src[i];
    } else {
      const f32x4 z = {0.f, 0.f, 0.f, 0.f};
      #pragma unroll
      for (int i = 0; i < 4; ++i) dst[i] = z;
    }
  }
  for (int layer = 0; layer < 3; ++layer) {       // each WG does tile rr=wg of each layer
    const float* W = (layer == 0) ? W1 : ((layer == 1) ? W2 : W3);
    const int tk = (wg >> 3) * 64, tn = (wg & 7) * 64;
    {
      const int lr = threadIdx.x >> 3, lc = (threadIdx.x & 7) * 8;
      const f32x4* src = (const f32x4*)(W + (size_t)(tk + lr) * S + tn + lc);
      f32x4 a = src[0], b = src[1];
      #pragma unroll
      for (int e = 0; e < 4; ++e) { strans[lr][lc + e] = a[e]; strans[lr][lc + 4 + e] = b[e]; }
    }
    __syncthreads();
    {
      const int n = threadIdx.x & 63, g = threadIdx.x >> 6;
      short8 p;
      #pragma unroll
      for (int j = 0; j < 8; ++j) p[j] = f2bf(strans[g * 8 + j][n]);
      *(short8*)(Wb + (size_t)layer * S * S + (size_t)(tn + n) * S + tk + g * 8) = p;
    }
    __syncthreads();
  }
  gbar(ctr, target);                                         // barrier 1

  // ---- Phase B: f0 -> slot0; partials for d0, d1 ----
  build_act(A, yloc, kloc, nullptr, 0, 0, 6, 0.f, nullptr);
  feval3(A, B, Wb, b1, b2, b3, kloc + (size_t)0 * KSZ);
  {
    float sy, sf;
    sumsq_init(yloc, kloc, sy, sf);
    float p0 = block_sum(sy, sred);
    float p1 = block_sum(sf, sred);
    if (threadIdx.x == 0) { red[wg] = p0; red[64 + wg] = p1; }
  }
  gbar(ctr, target);                                         // barrier 2

  if (threadIdx.x == 0) {
    float a = 0.f, b = 0.f;
    for (int i = 0; i < NBLK; ++i) { a += red[i]; b += red[64 + i]; }
    float d0 = sqrtf(a / NELEMF), d1 = sqrtf(b / NELEMF);
    float h0 = (fminf(d0, d1) < 1e-5f) ? 1e-6f : 0.01f * d0 / fmaxf(d1, 1e-12f);
    sbc[0] = h0; sbc[1] = d1;
  }
  __syncthreads();
  const float h0  = sbc[0];
  const float d1s = sbc[1];
  __syncthreads();

  // ---- Phase C: f1 = f(y0 + h0*f0) -> slot1; partial for d2 ----
  {
    const float onec[1] = {1.f};
    build_act(A, yloc, kloc, onec, 1, 0, 6, h0, nullptr);
  }
  feval3(A, B, Wb, b1, b2, b3, kloc + (size_t)1 * KSZ);
  {
    float sd = sumsq_d2(yloc, kloc, kloc + (size_t)1 * KSZ);
    float p2 = block_sum(sd, sred);
    if (threadIdx.x == 0) red[128 + wg] = p2;
  }
  gbar(ctr, target);                                         // barrier 3

  if (threadIdx.x == 0) {
    float s = 0.f;
    for (int i = 0; i < NBLK; ++i) s += red[128 + i];
    float d2 = sqrtf(s / NELEMF) / h0;
    float dmax = fmaxf(d1s, d2);
    float h1 = (dmax <= 1e-15f) ? fmaxf(1e-6f, h0 * 1e-3f)
                                : powf(0.01f / fmaxf(dmax, 1e-12f), 0.2f);
    sbc[0] = fminf(fminf(100.f * h0, h1), 1.f);
  }
  __syncthreads();
  float dt = sbc[0];
  __syncthreads();

  // ---- Integration loop (<=20 steps, 1 grid barrier each) ----
  float tcur = 0.f;
  int done = 0;
  int s1 = 0, s7 = 6;
  for (int step = 0; step < 20; ++step) {
    const float dtc = fminf(dt, 1.f - tcur);
    build_act(A, yloc, kloc, C_A2, 1, s1, s7, dtc, nullptr);
    feval3(A, B, Wb, b1, b2, b3, kloc + (size_t)1 * KSZ);
    build_act(A, yloc, kloc, C_A3, 2, s1, s7, dtc, nullptr);
    feval3(A, B, Wb, b1, b2, b3, kloc + (size_t)2 * KSZ);
    build_act(A, yloc, kloc, C_A4, 3, s1, s7, dtc, nullptr);
    feval3(A, B, Wb, b1, b2, b3, kloc + (size_t)3 * KSZ);
    build_act(A, yloc, kloc, C_A5, 4, s1, s7, dtc, nullptr);
    feval3(A, B, Wb, b1, b2, b3, kloc + (size_t)4 * KSZ);
    build_act(A, yloc, kloc, C_A6, 5, s1, s7, dtc, nullptr);
    feval3(A, B, Wb, b1, b2, b3, kloc + (size_t)5 * KSZ);
    build_act(A, yloc, kloc, C_B5, 6, s1, s7, dtc, yAlt);    // y5 -> yAlt
    feval3(A, B, Wb, b1, b2, b3, kloc + (size_t)s7 * KSZ);   // k7 (FSAL)

    {
      float ep = sumsq_err(yloc, yAlt, kloc, s1, s7, dtc);
      float p = block_sum(ep, sred);
      if (threadIdx.x == 0) red[192 + step * 64 + wg] = p;
    }
    gbar(ctr, target);                                       // per-step barrier

    if (threadIdx.x == 0) {
      float es = 0.f;
      for (int i = 0; i < NBLK; ++i) es += red[192 + step * 64 + i];
      sbc[0] = sqrtf(es / NELEMF);
    }
    __syncthreads();
    const float err_norm = sbc[0];
    __syncthreads();

    const int accept = (err_norm <= 1.0f);
    const float en = fmaxf(err_norm, 1e-10f);
    float fac = 0.9f * powf(en, -0.2f);
    fac = fminf(fmaxf(fac, 0.2f), 10.0f);
    const float dt_next = dtc * fac;
    const int done_new = done | (accept && (tcur + dtc >= 1.f - 1e-7f));
    if (!done) {
      if (accept) {
        tcur += dtc;
        float* tp = yloc; yloc = yAlt; yAlt = tp;
        int ts = s1; s1 = s7; s7 = ts;
      }
      dt = dt_next;
    }
    done = done_new;
    if (done) break;
  }

  // ---- final: ensure result is in d_out ----
  if (yloc != out + (size_t)r0 * S) {
    const int t = threadIdx.x;
    const size_t off = (size_t)(t >> 5) * S + ((t & 31) << 4);
    const f32x4* src = (const f32x4*)(yloc + off);
    f32x4* dst = (f32x4*)(out + (size_t)r0 * S + off);
    #pragma unroll
    for (int i = 0; i < 4; ++i) dst[i] = src[i];
  }
}

extern "C" void kernel_launch(void* const* d_in, const int* in_sizes, int n_in,
                              void* d_out, int out_size, void* d_ws, size_t ws_size,
                              hipStream_t stream) {
  const float* x  = (const float*)d_in[0];
  const float* W1 = (const float*)d_in[1];
  const float* b1 = (const float*)d_in[2];
  const float* W2 = (const float*)d_in[3];
  const float* b2 = (const float*)d_in[4];
  const float* W3 = (const float*)d_in[5];
  const float* b3 = (const float*)d_in[6];
  unsigned char* ws = (unsigned char*)d_ws;

  hipLaunchKernelGGL(node_zero, dim3(1), dim3(64), 0, stream, (unsigned*)(ws + CTR_OFF));
  hipLaunchKernelGGL(node_main, dim3(NBLK), dim3(NTHR), 0, stream,
                     x, W1, b1, W2, b2, W3, b3, (float*)d_out, ws);
}